// Round 3
// baseline (108.276 us; speedup 1.0000x reference)
//
#include <hip/hip_runtime.h>

constexpr int BLOCK = 256;
constexpr int TY    = 16;          // threads along rec rows (lane bits 0..3)
constexpr int TX    = 16;          // threads along data cols
constexpr int RPT   = 8;           // rec points per thread (persistent regs)
constexpr int CPT   = 8;           // data cols per thread per step
constexpr int RECB  = TY * RPT;    // 128 rec rows per block
constexpr int STEPC = TX * CPT;    // 128 data cols per step
constexpr int CHUNK = 4096;        // data points staged in LDS (64 KB)

// Fused kernel: each unique distance computed ONCE, feeding both the
// rec->data min (rowmin) and the data->rec min (colmin).
//   t   = |q|^2 - 2 q.p          (3 fma, chain based at qw)
//   u   = t + |p|^2 = d          (rowmin over u; complete per block)
//   colmin over t                (|p|^2 deferred to stage 2; partial per block)
__global__ __launch_bounds__(BLOCK, 1)
void chamfer_fused_kernel(const float* __restrict__ rec,
                          const float* __restrict__ data,
                          float* __restrict__ colpart,   // [B*RB][M]
                          float* __restrict__ rowsums,   // [B*RB]
                          int N, int M)
{
    __shared__ float4 pts[CHUNK];   // 64 KB; reused as float buf at the end

    const int tid = threadIdx.x;
    const int ty  = tid & (TY - 1);          // lane bits 0..3 -> intra-wave shfl
    const int tx  = tid >> 4;

    const int RB = N / RECB;
    const int b  = blockIdx.x / RB;
    const int rb = blockIdx.x % RB;

    const float* __restrict__ qb = rec  + ((size_t)b * N + (size_t)rb * RECB) * 3;
    const float* __restrict__ pb = data + (size_t)b * M * 3;

    float qx[RPT], qy[RPT], qz[RPT], qw[RPT], rmin[RPT];
    #pragma unroll
    for (int i = 0; i < RPT; ++i) {
        const float* qp = qb + (size_t)(ty * RPT + i) * 3;
        qx[i] = qp[0]; qy[i] = qp[1]; qz[i] = qp[2];
        qw[i] = fmaf(qx[i], qx[i], fmaf(qy[i], qy[i], qz[i] * qz[i]));
        rmin[i] = 3.4e38f;
    }

    for (int c0 = 0; c0 < M; c0 += CHUNK) {
        __syncthreads();
        for (int j = tid; j < CHUNK; j += BLOCK) {
            const float* pp = pb + (size_t)(c0 + j) * 3;
            const float px = pp[0], py = pp[1], pz = pp[2];
            pts[j] = make_float4(-2.f * px, -2.f * py, -2.f * pz,
                                 fmaf(px, px, fmaf(py, py, pz * pz)));
        }
        __syncthreads();

        #pragma unroll 2
        for (int s = 0; s < CHUNK; s += STEPC) {
            const float4* __restrict__ pp = &pts[s + tx * CPT];
            float cmin[CPT];
            #pragma unroll
            for (int c = 0; c < CPT; ++c) {
                const float4 p = pp[c];
                float t[RPT];
                #pragma unroll
                for (int i = 0; i < RPT; ++i) {
                    float v = fmaf(qz[i], p.z, qw[i]);
                    v = fmaf(qy[i], p.y, v);
                    v = fmaf(qx[i], p.x, v);
                    t[i] = v;
                    rmin[i] = fminf(rmin[i], v + p.w);   // full distance
                }
                cmin[c] = fminf(fminf(fminf(t[0], t[1]), fminf(t[2], t[3])),
                                fminf(fminf(t[4], t[5]), fminf(t[6], t[7])));
            }
            // cross-ty colmin reduce (intra-wave: ty = lane bits 0..3)
            #pragma unroll
            for (int c = 0; c < CPT; ++c) {
                float v = cmin[c];
                v = fminf(v, __shfl_xor(v, 1));
                v = fminf(v, __shfl_xor(v, 2));
                v = fminf(v, __shfl_xor(v, 4));
                v = fminf(v, __shfl_xor(v, 8));
                cmin[c] = v;
            }
            if (ty == 0) {
                float* outp = colpart + (size_t)blockIdx.x * M + (c0 + s + tx * CPT);
                *(float4*)(outp + 0) = make_float4(cmin[0], cmin[1], cmin[2], cmin[3]);
                *(float4*)(outp + 4) = make_float4(cmin[4], cmin[5], cmin[6], cmin[7]);
            }
        }
    }

    // rowmin: reduce across tx (16 partials per row) via LDS, then block-sum
    __syncthreads();
    float* rbuf = (float*)pts;                 // 16384 floats available
    #pragma unroll
    for (int i = 0; i < RPT; ++i)
        rbuf[tx * RECB + ty * RPT + i] = rmin[i];
    __syncthreads();

    float rsum = 0.f;
    if (tid < RECB) {
        float v = rbuf[tid];
        for (int x = 1; x < TX; ++x) v = fminf(v, rbuf[x * RECB + tid]);
        rsum = fmaxf(v, 0.f);                  // clamp after full min
    }
    for (int off = 32; off; off >>= 1) rsum += __shfl_down(rsum, off);
    if ((tid & 63) == 0) rbuf[4096 + (tid >> 6)] = rsum;
    __syncthreads();
    if (tid == 0)
        rowsums[blockIdx.x] = rbuf[4096] + rbuf[4097] + rbuf[4098] + rbuf[4099];
}

// Stage 2: per (batch, col): min over RB partials, add |p|^2, clamp, block-sum.
__global__ __launch_bounds__(256)
void chamfer_colreduce_kernel(const float* __restrict__ data,
                              const float* __restrict__ colpart,
                              float* __restrict__ colsums,
                              int M, int RB)
{
    __shared__ float wsum[4];
    const int g = blockIdx.x * 256 + threadIdx.x;    // b*M + j
    const int b = g / M, j = g - b * M;

    float v = 3.4e38f;
    const float* cp = colpart + ((size_t)b * RB) * M + j;
    for (int r = 0; r < RB; ++r) v = fminf(v, cp[(size_t)r * M]);

    const float* pp = data + (size_t)g * 3;
    const float pw = fmaf(pp[0], pp[0], fmaf(pp[1], pp[1], pp[2] * pp[2]));
    float d = fmaxf(v + pw, 0.f);

    for (int off = 32; off; off >>= 1) d += __shfl_down(d, off);
    if ((threadIdx.x & 63) == 0) wsum[threadIdx.x >> 6] = d;
    __syncthreads();
    if (threadIdx.x == 0)
        colsums[blockIdx.x] = wsum[0] + wsum[1] + wsum[2] + wsum[3];
}

// Finalize: mean_b( max(rowsum_b/N, colsum_b/M) )
__global__ __launch_bounds__(256)
void chamfer_finalize(const float* __restrict__ rowsums,
                      const float* __restrict__ colsums,
                      float* __restrict__ out,
                      int N, int M, int B, int RB, int CB)
{
    __shared__ float seg[8];
    const int tid = threadIdx.x;
    if (tid < 2 * B) {
        const int dir = tid / B, b = tid % B;
        float s = 0.f;
        if (dir == 0) for (int i = 0; i < RB; ++i) s += rowsums[b * RB + i];
        else          for (int i = 0; i < CB; ++i) s += colsums[b * CB + i];
        seg[tid] = s;
    }
    __syncthreads();
    if (tid == 0) {
        float acc = 0.f;
        for (int b = 0; b < B; ++b)
            acc += fmaxf(seg[b] / (float)N, seg[B + b] / (float)M);
        out[0] = acc / (float)B;
    }
}

extern "C" void kernel_launch(void* const* d_in, const int* in_sizes, int n_in,
                              void* d_out, int out_size, void* d_ws, size_t ws_size,
                              hipStream_t stream)
{
    const float* rec  = (const float*)d_in[0];
    const float* data = (const float*)d_in[1];
    const int B = 4;
    const int N = in_sizes[0] / (B * 3);
    const int M = in_sizes[1] / (B * 3);
    const int RB = N / RECB;                  // 64 rec-blocks per batch
    const int CB = M / 256;                   // stage-2 blocks per batch

    float* colpart = (float*)d_ws;                        // [B*RB][M]
    float* rowsums = colpart + (size_t)B * RB * M;        // [B*RB]
    float* colsums = rowsums + (size_t)B * RB;            // [B*CB]

    chamfer_fused_kernel<<<B * RB, BLOCK, 0, stream>>>(rec, data, colpart,
                                                       rowsums, N, M);
    chamfer_colreduce_kernel<<<B * CB, 256, 0, stream>>>(data, colpart, colsums,
                                                         M, RB);
    chamfer_finalize<<<1, 256, 0, stream>>>(rowsums, colsums, (float*)d_out,
                                            N, M, B, RB, CB);
}

// Round 4
// 57.524 us; speedup vs baseline: 1.8823x; 1.8823x over previous
//
#include <hip/hip_runtime.h>

constexpr int BLOCK = 256;
constexpr int QPT   = 8;              // queries per thread (register tile)
constexpr int QPB   = BLOCK * QPT;    // 2048 queries per block

// Stage 1: partial per-query min over one point-slice.
// Points pre-transformed in LDS to (-2px, -2py, -2pz, |p|^2) so each
// distance (minus the deferred |q|^2 term) is 3 fma; point-pairs share the
// min-accumulate: fminf(fminf(t0,t1), mn) -> v_min3_f32 (3.5 ops/dist).
__global__ __launch_bounds__(BLOCK, 8)
void chamfer_partial_kernel(const float* __restrict__ rec,
                            const float* __restrict__ data,
                            float* __restrict__ partial,   // [S][TOTQ]
                            int N, int M, int B, int S)
{
    extern __shared__ float4 pts[];    // slice points, transformed

    const int bid = blockIdx.x;
    const int qb  = bid / S;           // query-block index
    const int s   = bid % S;           // point-slice index
    const int q0  = qb * QPB;
    const int TOTQ0 = B * N;
    const int TOTQ  = B * (N + M);

    const bool dir1 = q0 >= TOTQ0;
    const int  lq0  = dir1 ? q0 - TOTQ0 : q0;
    const int  Nq   = dir1 ? M : N;
    const int  Np   = dir1 ? N : M;
    const int  b    = lq0 / Nq;

    const float* __restrict__ qbase =
        (dir1 ? data : rec) + ((size_t)b * Nq + (lq0 % Nq)) * 3;
    const float* __restrict__ pbase =
        (dir1 ? rec : data) + (size_t)b * Np * 3;

    const int slice = Np / S;
    const int p0    = s * slice;

    for (int j = threadIdx.x; j < slice; j += BLOCK) {
        const float* pp = pbase + (size_t)(p0 + j) * 3;
        const float px = pp[0], py = pp[1], pz = pp[2];
        pts[j] = make_float4(-2.f * px, -2.f * py, -2.f * pz,
                             fmaf(px, px, fmaf(py, py, pz * pz)));
    }
    __syncthreads();

    float qx[QPT], qy[QPT], qz[QPT], mn[QPT];
    #pragma unroll
    for (int k = 0; k < QPT; ++k) {
        const float* qp = qbase + (size_t)(k * BLOCK + threadIdx.x) * 3;
        qx[k] = qp[0]; qy[k] = qp[1]; qz[k] = qp[2];
        mn[k] = 3.4e38f;
    }

    #pragma unroll 2
    for (int j = 0; j < slice; j += 2) {
        const float4 p0v = pts[j];
        const float4 p1v = pts[j + 1];
        #pragma unroll
        for (int k = 0; k < QPT; ++k) {
            float t0 = fmaf(qz[k], p0v.z, p0v.w);
            t0 = fmaf(qy[k], p0v.y, t0);
            t0 = fmaf(qx[k], p0v.x, t0);
            float t1 = fmaf(qz[k], p1v.z, p1v.w);
            t1 = fmaf(qy[k], p1v.y, t1);
            t1 = fmaf(qx[k], p1v.x, t1);
            mn[k] = fminf(fminf(t0, t1), mn[k]);   // -> v_min3_f32
        }
    }

    float* out = partial + (size_t)s * TOTQ + q0;
    #pragma unroll
    for (int k = 0; k < QPT; ++k)
        out[k * BLOCK + threadIdx.x] = mn[k];
}

// Stage 2: per query, min across S slices, add |q|^2, clamp, block-sum.
__global__ __launch_bounds__(BLOCK)
void chamfer_reduce_kernel(const float* __restrict__ rec,
                           const float* __restrict__ data,
                           const float* __restrict__ partial,
                           float* __restrict__ block_sums,
                           int N, int M, int B, int S)
{
    __shared__ float wsum[BLOCK / 64];
    const int q = blockIdx.x * BLOCK + threadIdx.x;
    const int TOTQ0 = B * N;
    const int TOTQ  = B * (N + M);

    float m0 = 3.4e38f, m1 = 3.4e38f, m2 = 3.4e38f, m3 = 3.4e38f;
    int s = 0;
    for (; s + 4 <= S; s += 4) {
        m0 = fminf(m0, partial[(size_t)(s + 0) * TOTQ + q]);
        m1 = fminf(m1, partial[(size_t)(s + 1) * TOTQ + q]);
        m2 = fminf(m2, partial[(size_t)(s + 2) * TOTQ + q]);
        m3 = fminf(m3, partial[(size_t)(s + 3) * TOTQ + q]);
    }
    for (; s < S; ++s) m0 = fminf(m0, partial[(size_t)s * TOTQ + q]);
    float mn = fminf(fminf(m0, m1), fminf(m2, m3));

    const bool dir1 = q >= TOTQ0;
    const int  lq   = dir1 ? q - TOTQ0 : q;
    const float* qp = (dir1 ? data : rec) + (size_t)lq * 3;
    const float q2  = fmaf(qp[0], qp[0], fmaf(qp[1], qp[1], qp[2] * qp[2]));
    float d = fmaxf(mn + q2, 0.0f);

    for (int off = 32; off; off >>= 1) d += __shfl_down(d, off);
    if ((threadIdx.x & 63) == 0) wsum[threadIdx.x >> 6] = d;
    __syncthreads();
    if (threadIdx.x == 0) {
        float ssum = 0.f;
        for (int w = 0; w < BLOCK / 64; ++w) ssum += wsum[w];
        block_sums[blockIdx.x] = ssum;
    }
}

// Finalize: mean_b( max(sum_rec/N, sum_data/M) )
__global__ __launch_bounds__(256)
void chamfer_finalize(const float* __restrict__ bs, float* __restrict__ out,
                      int N, int M, int B)
{
    __shared__ float smem[256];
    __shared__ float seg[16];
    const int nb0 = N / BLOCK, nb1 = M / BLOCK;
    const int nblk = B * (nb0 + nb1);
    const int tid = threadIdx.x;
    smem[tid] = (tid < nblk) ? bs[tid] : 0.f;
    __syncthreads();
    if (tid < 2 * B) {
        const int dir = tid / B, b = tid % B;
        const int cnt = dir ? nb1 : nb0;
        const int off = dir ? B * nb0 + b * nb1 : b * nb0;
        float v = 0.f;
        for (int i = 0; i < cnt; ++i) v += smem[off + i];
        seg[tid] = v;
    }
    __syncthreads();
    if (tid == 0) {
        float acc = 0.f;
        for (int b = 0; b < B; ++b)
            acc += fmaxf(seg[b] / (float)N, seg[B + b] / (float)M);
        out[0] = acc / (float)B;
    }
}

extern "C" void kernel_launch(void* const* d_in, const int* in_sizes, int n_in,
                              void* d_out, int out_size, void* d_ws, size_t ws_size,
                              hipStream_t stream)
{
    const float* rec  = (const float*)d_in[0];
    const float* data = (const float*)d_in[1];
    const int B = 4;
    const int N = in_sizes[0] / (B * 3);
    const int M = in_sizes[1] / (B * 3);
    const int TOTQ = B * (N + M);

    // Largest point-split S (power of 2, >= queries parallelism target)
    // whose partial array fits d_ws. S=64 -> grid 2048 = 8 blocks/CU.
    int S = 64;
    const int nblk2 = TOTQ / BLOCK;                    // stage-2 blocks
    while (S > 1 &&
           (size_t)S * TOTQ * sizeof(float) + (size_t)nblk2 * sizeof(float) > ws_size)
        S >>= 1;

    float* partial    = (float*)d_ws;                  // [S][TOTQ]
    float* block_sums = partial + (size_t)S * TOTQ;    // [nblk2]

    const int grid1   = (TOTQ / QPB) * S;
    const int maxNp   = (N > M) ? N : M;
    const size_t lds1 = (size_t)(maxNp / S) * sizeof(float4);

    chamfer_partial_kernel<<<grid1, BLOCK, lds1, stream>>>(rec, data, partial,
                                                           N, M, B, S);
    chamfer_reduce_kernel<<<nblk2, BLOCK, 0, stream>>>(rec, data, partial,
                                                       block_sums, N, M, B, S);
    chamfer_finalize<<<1, 256, 0, stream>>>(block_sums, (float*)d_out, N, M, B);
}

// Round 5
// 54.740 us; speedup vs baseline: 1.9780x; 1.0509x over previous
//
#include <hip/hip_runtime.h>

constexpr int BLOCK = 256;
constexpr int QPT   = 8;              // queries per thread (register tile)
constexpr int QPB   = BLOCK * QPT;    // 2048 queries per block

// Stage 1: partial per-query min over one point-slice.
// Points pre-transformed in LDS to (-2px, -2py, -2pz, |p|^2) so each
// distance (minus the deferred |q|^2 term) is 3 fma; point-pairs share the
// min-accumulate: fminf(fminf(t0,t1), mn) -> v_min3_f32 (3.5 ops/dist).
// The empty asm pins all 8 accumulators live at one point per iteration,
// preventing the scheduler from fissioning the loop into low-VGPR passes
// (r4 evidence: VGPR_Count=28 < the ~46 the written loop needs).
__global__ __launch_bounds__(BLOCK, 4)
void chamfer_partial_kernel(const float* __restrict__ rec,
                            const float* __restrict__ data,
                            float* __restrict__ partial,   // [S][TOTQ]
                            int N, int M, int B, int S)
{
    extern __shared__ float4 pts[];    // slice points, transformed

    const int bid = blockIdx.x;
    const int qb  = bid / S;           // query-block index
    const int s   = bid % S;           // point-slice index
    const int q0  = qb * QPB;
    const int TOTQ0 = B * N;
    const int TOTQ  = B * (N + M);

    const bool dir1 = q0 >= TOTQ0;
    const int  lq0  = dir1 ? q0 - TOTQ0 : q0;
    const int  Nq   = dir1 ? M : N;
    const int  Np   = dir1 ? N : M;
    const int  b    = lq0 / Nq;

    const float* __restrict__ qbase =
        (dir1 ? data : rec) + ((size_t)b * Nq + (lq0 % Nq)) * 3;
    const float* __restrict__ pbase =
        (dir1 ? rec : data) + (size_t)b * Np * 3;

    const int slice = Np / S;
    const int p0    = s * slice;

    for (int j = threadIdx.x; j < slice; j += BLOCK) {
        const float* pp = pbase + (size_t)(p0 + j) * 3;
        const float px = pp[0], py = pp[1], pz = pp[2];
        pts[j] = make_float4(-2.f * px, -2.f * py, -2.f * pz,
                             fmaf(px, px, fmaf(py, py, pz * pz)));
    }
    __syncthreads();

    float qx[QPT], qy[QPT], qz[QPT], mn[QPT];
    #pragma unroll
    for (int k = 0; k < QPT; ++k) {
        const float* qp = qbase + (size_t)(k * BLOCK + threadIdx.x) * 3;
        qx[k] = qp[0]; qy[k] = qp[1]; qz[k] = qp[2];
        mn[k] = 3.4e38f;
    }

    #pragma unroll 2
    for (int j = 0; j < slice; j += 2) {
        const float4 p0v = pts[j];
        const float4 p1v = pts[j + 1];
        #pragma unroll
        for (int k = 0; k < QPT; ++k) {
            float t0 = fmaf(qz[k], p0v.z, p0v.w);
            t0 = fmaf(qy[k], p0v.y, t0);
            t0 = fmaf(qx[k], p0v.x, t0);
            float t1 = fmaf(qz[k], p1v.z, p1v.w);
            t1 = fmaf(qy[k], p1v.y, t1);
            t1 = fmaf(qx[k], p1v.x, t1);
            mn[k] = fminf(fminf(t0, t1), mn[k]);   // -> v_min3_f32
        }
        // Pin: all 8 accumulators live HERE, every iteration -> no fission.
        asm volatile("" : "+v"(mn[0]), "+v"(mn[1]), "+v"(mn[2]), "+v"(mn[3]),
                          "+v"(mn[4]), "+v"(mn[5]), "+v"(mn[6]), "+v"(mn[7]));
    }

    float* out = partial + (size_t)s * TOTQ + q0;
    #pragma unroll
    for (int k = 0; k < QPT; ++k)
        out[k * BLOCK + threadIdx.x] = mn[k];
}

// Stage 2: per query, min across S slices, add |q|^2, clamp, block-sum.
__global__ __launch_bounds__(BLOCK)
void chamfer_reduce_kernel(const float* __restrict__ rec,
                           const float* __restrict__ data,
                           const float* __restrict__ partial,
                           float* __restrict__ block_sums,
                           int N, int M, int B, int S)
{
    __shared__ float wsum[BLOCK / 64];
    const int q = blockIdx.x * BLOCK + threadIdx.x;
    const int TOTQ0 = B * N;
    const int TOTQ  = B * (N + M);

    float m0 = 3.4e38f, m1 = 3.4e38f, m2 = 3.4e38f, m3 = 3.4e38f;
    int s = 0;
    for (; s + 4 <= S; s += 4) {
        m0 = fminf(m0, partial[(size_t)(s + 0) * TOTQ + q]);
        m1 = fminf(m1, partial[(size_t)(s + 1) * TOTQ + q]);
        m2 = fminf(m2, partial[(size_t)(s + 2) * TOTQ + q]);
        m3 = fminf(m3, partial[(size_t)(s + 3) * TOTQ + q]);
    }
    for (; s < S; ++s) m0 = fminf(m0, partial[(size_t)s * TOTQ + q]);
    float mn = fminf(fminf(m0, m1), fminf(m2, m3));

    const bool dir1 = q >= TOTQ0;
    const int  lq   = dir1 ? q - TOTQ0 : q;
    const float* qp = (dir1 ? data : rec) + (size_t)lq * 3;
    const float q2  = fmaf(qp[0], qp[0], fmaf(qp[1], qp[1], qp[2] * qp[2]));
    float d = fmaxf(mn + q2, 0.0f);

    for (int off = 32; off; off >>= 1) d += __shfl_down(d, off);
    if ((threadIdx.x & 63) == 0) wsum[threadIdx.x >> 6] = d;
    __syncthreads();
    if (threadIdx.x == 0) {
        float ssum = 0.f;
        for (int w = 0; w < BLOCK / 64; ++w) ssum += wsum[w];
        block_sums[blockIdx.x] = ssum;
    }
}

// Finalize: mean_b( max(sum_rec/N, sum_data/M) )
__global__ __launch_bounds__(256)
void chamfer_finalize(const float* __restrict__ bs, float* __restrict__ out,
                      int N, int M, int B)
{
    __shared__ float smem[256];
    __shared__ float seg[16];
    const int nb0 = N / BLOCK, nb1 = M / BLOCK;
    const int nblk = B * (nb0 + nb1);
    const int tid = threadIdx.x;
    smem[tid] = (tid < nblk) ? bs[tid] : 0.f;
    __syncthreads();
    if (tid < 2 * B) {
        const int dir = tid / B, b = tid % B;
        const int cnt = dir ? nb1 : nb0;
        const int off = dir ? B * nb0 + b * nb1 : b * nb0;
        float v = 0.f;
        for (int i = 0; i < cnt; ++i) v += smem[off + i];
        seg[tid] = v;
    }
    __syncthreads();
    if (tid == 0) {
        float acc = 0.f;
        for (int b = 0; b < B; ++b)
            acc += fmaxf(seg[b] / (float)N, seg[B + b] / (float)M);
        out[0] = acc / (float)B;
    }
}

extern "C" void kernel_launch(void* const* d_in, const int* in_sizes, int n_in,
                              void* d_out, int out_size, void* d_ws, size_t ws_size,
                              hipStream_t stream)
{
    const float* rec  = (const float*)d_in[0];
    const float* data = (const float*)d_in[1];
    const int B = 4;
    const int N = in_sizes[0] / (B * 3);
    const int M = in_sizes[1] / (B * 3);
    const int TOTQ = B * (N + M);

    // S=32 -> grid 1024 = exactly 4 blocks/CU (matches __launch_bounds__ min
    // waves), one full resident generation, no tail.
    int S = 32;
    const int nblk2 = TOTQ / BLOCK;                    // stage-2 blocks
    while (S > 1 &&
           (size_t)S * TOTQ * sizeof(float) + (size_t)nblk2 * sizeof(float) > ws_size)
        S >>= 1;

    float* partial    = (float*)d_ws;                  // [S][TOTQ]
    float* block_sums = partial + (size_t)S * TOTQ;    // [nblk2]

    const int grid1   = (TOTQ / QPB) * S;
    const int maxNp   = (N > M) ? N : M;
    const size_t lds1 = (size_t)(maxNp / S) * sizeof(float4);

    chamfer_partial_kernel<<<grid1, BLOCK, lds1, stream>>>(rec, data, partial,
                                                           N, M, B, S);
    chamfer_reduce_kernel<<<nblk2, BLOCK, 0, stream>>>(rec, data, partial,
                                                       block_sums, N, M, B, S);
    chamfer_finalize<<<1, 256, 0, stream>>>(block_sums, (float*)d_out, N, M, B);
}